// Round 4
// baseline (355.507 us; speedup 1.0000x reference)
//
#include <hip/hip_runtime.h>
#include <hip/hip_bf16.h>
#include <stdint.h>

typedef _Float16 f16;
typedef _Float16 f16x4 __attribute__((ext_vector_type(4)));
typedef _Float16 f16x8 __attribute__((ext_vector_type(8)));
typedef float f32x4 __attribute__((ext_vector_type(4)));

// async global->LDS copy, 16B per lane. LDS dest must be wave-uniform-base + lane*16.
#define ASYNC_COPY16(gsrc, ldst)                                                   \
    __builtin_amdgcn_global_load_lds(                                              \
        (__attribute__((address_space(1))) void*)(gsrc),                           \
        (__attribute__((address_space(3))) void*)(ldst), 16, 0, 0)

// ---------------------------------------------------------------------------
// fp32 -> f16 conversion, 4 elems/thread
// ---------------------------------------------------------------------------
__global__ __launch_bounds__(256) void cvt_f32_to_f16(const float* __restrict__ in,
                                                      f16* __restrict__ out, int n4) {
    int i = blockIdx.x * 256 + threadIdx.x;
    if (i >= n4) return;
    float4 v = ((const float4*)in)[i];
    f16x4 o;
    o.x = (f16)v.x; o.y = (f16)v.y; o.z = (f16)v.z; o.w = (f16)v.w;
    ((f16x4*)out)[i] = o;
}

// three conversions in one launch: y -> yb, W1 -> w1b, W2 -> w2b
__global__ __launch_bounds__(256) void cvt3_f32_to_f16(const float* __restrict__ y,
                                                       const float* __restrict__ W1,
                                                       const float* __restrict__ W2,
                                                       f16* __restrict__ yb,
                                                       f16* __restrict__ w1b,
                                                       f16* __restrict__ w2b,
                                                       int nY4, int nW4) {
    int i = blockIdx.x * 256 + threadIdx.x;
    const float* src;
    f16* dst;
    int off;
    if (i < nY4) {
        src = y; dst = yb; off = i;
    } else if (i < nY4 + nW4) {
        src = W1; dst = w1b; off = i - nY4;
    } else {
        src = W2; dst = w2b; off = i - nY4 - nW4;
        if (off >= nW4) return;
    }
    float4 v = ((const float4*)src)[off];
    f16x4 o;
    o.x = (f16)v.x; o.y = (f16)v.y; o.z = (f16)v.z; o.w = (f16)v.w;
    ((f16x4*)dst)[off] = o;
}

// ---------------------------------------------------------------------------
// C = A(MxK) * B(NxK)^T + bias, f16 in, fp32 accumulate.
// Tile 128x128, 4 waves (2x2) of 64x64 (4x4 16x16x32 MFMAs). BK=64 dbuf LDS,
// one barrier/iter, XOR-swizzled segments (round 3: 0 bank conflicts).
//
// NEW round 4:
//  * XCD-aware tile remap: physical block p -> xcd = p&7 owns a contiguous
//    4-column x 16-row tile group, so each XCD's per-iter distinct fill slice
//    (A 256 KB + B 64 KB) is L2-resident -> cuts L3->L2 fill traffic ~2.4x.
//    (Tests the "fill is L3-BW-bound" theory; assignment is a perf heuristic
//    only — correctness doesn't depend on it.)
//  * FUSE_DOT (GEMM2): epilogue computes per-row partial dot(y, out) over the
//    block's 128-col span and atomicAdds into dotv[M] (zeroed via memset).
// ---------------------------------------------------------------------------
template <int STORE_F16, int FUSE_DOT>
__global__ __launch_bounds__(256) void gemm_bt(const f16* __restrict__ A,
                                               const f16* __restrict__ Bm,
                                               const float* __restrict__ bias,
                                               void* __restrict__ Cout,
                                               const float* __restrict__ Yf,
                                               float* __restrict__ dotv,
                                               int M, int N, int K) {
    constexpr int BM = 128, BN = 128, BK = 64;
    __shared__ __align__(16) f16 sA[2][BM * BK];  // 2 x 16 KB
    __shared__ __align__(16) f16 sB[2][BN * BK];  // 2 x 16 KB

    const int tid   = threadIdx.x;
    const int lane  = tid & 63;
    const int wave  = tid >> 6;   // 0..3
    const int waveM = wave >> 1;  // 0..1
    const int waveN = wave & 1;   // 0..1

    // ---- XCD-aware tile remap (assumes round-robin p%8 -> XCD; heuristic) ----
    int bxt, byt;
    {
        const int p = blockIdx.y * gridDim.x + blockIdx.x;
        if ((gridDim.x & 7) == 0) {
            const int xcd  = p & 7;
            const int slot = p >> 3;
            const int cpx  = gridDim.x >> 3;           // col-tiles per XCD
            const int c    = slot / gridDim.y;         // 0..cpx-1
            const int r    = slot - c * gridDim.y;     // 0..gridDim.y-1
            bxt = xcd * cpx + c;
            byt = r;
        } else {
            bxt = blockIdx.x;
            byt = blockIdx.y;
        }
    }
    const int bm = byt * BM;
    const int bn = bxt * BN;

    const f16* Aptr = A + (size_t)bm * K;
    const f16* Bptr = Bm + (size_t)bn * K;

    // staging: chunk j covers rows [j*32, j*32+32); thread t writes LDS halves
    // [j*2048 + t*8, +8) (linear, as global_load_lds requires). Fetched global
    // segment is XOR-swizzled: seg = (t&7) ^ (row&7); undone at ds_read.
    const int srow_lo = tid >> 3;        // 0..31
    const int sseg    = tid & 7;         // 0..7

    f32x4 acc[4][4] = {};

    const int quad = lane >> 4;
    const int l16  = lane & 15;

    const int iters = K / BK;

    // prologue: stage iter 0 into buf 0
#pragma unroll
    for (int j = 0; j < 4; j++) {
        const int row = j * 32 + srow_lo;
        const int seg = sseg ^ (row & 7);
        ASYNC_COPY16(Aptr + (size_t)row * K + seg * 8, &sA[0][j * 2048 + tid * 8]);
    }
#pragma unroll
    for (int j = 0; j < 4; j++) {
        const int row = j * 32 + srow_lo;
        const int seg = sseg ^ (row & 7);
        ASYNC_COPY16(Bptr + (size_t)row * K + seg * 8, &sB[0][j * 2048 + tid * 8]);
    }

    int cur = 0;
    for (int it = 0; it < iters; ++it) {
        __syncthreads();  // drains vmcnt(0): buf[cur] ready

        if (it + 1 < iters) {
            const int k0 = (it + 1) * BK;
#pragma unroll
            for (int j = 0; j < 4; j++) {
                const int row = j * 32 + srow_lo;
                const int seg = sseg ^ (row & 7);
                ASYNC_COPY16(Aptr + (size_t)row * K + k0 + seg * 8,
                             &sA[cur ^ 1][j * 2048 + tid * 8]);
            }
#pragma unroll
            for (int j = 0; j < 4; j++) {
                const int row = j * 32 + srow_lo;
                const int seg = sseg ^ (row & 7);
                ASYNC_COPY16(Bptr + (size_t)row * K + k0 + seg * 8,
                             &sB[cur ^ 1][j * 2048 + tid * 8]);
            }
        }

#pragma unroll
        for (int h = 0; h < 2; h++) {
            f16x8 af[4], bf[4];
#pragma unroll
            for (int mi = 0; mi < 4; mi++) {
                const int row = waveM * 64 + mi * 16 + l16;
                const int seg = (h * 4 + quad) ^ (row & 7);
                af[mi] = *(const f16x8*)&sA[cur][row * BK + seg * 8];
            }
#pragma unroll
            for (int ni = 0; ni < 4; ni++) {
                const int row = waveN * 64 + ni * 16 + l16;
                const int seg = (h * 4 + quad) ^ (row & 7);
                bf[ni] = *(const f16x8*)&sB[cur][row * BK + seg * 8];
            }
#pragma unroll
            for (int mi = 0; mi < 4; mi++)
#pragma unroll
                for (int ni = 0; ni < 4; ni++)
                    acc[mi][ni] = __builtin_amdgcn_mfma_f32_16x16x32_f16(af[mi], bf[ni],
                                                                         acc[mi][ni], 0, 0, 0);
        }
        cur ^= 1;
        // single barrier/iter: next iteration's barrier (lgkmcnt+vmcnt drain)
        // protects buf reuse.
    }

    // epilogue: C/D layout col = lane&15, row = quad*4 + reg
#pragma unroll
    for (int mi = 0; mi < 4; mi++) {
#pragma unroll
        for (int r = 0; r < 4; r++) {
            const int row = bm + waveM * 64 + mi * 16 + quad * 4 + r;
            float rowsum = 0.f;
#pragma unroll
            for (int ni = 0; ni < 4; ni++) {
                const int col = bn + waveN * 64 + ni * 16 + l16;
                float v = acc[mi][ni][r] + bias[col];
                if (STORE_F16)
                    ((f16*)Cout)[(size_t)row * N + col] = (f16)v;
                else
                    ((float*)Cout)[(size_t)row * N + col] = v;
                if (FUSE_DOT) rowsum += v * Yf[(size_t)row * N + col];
            }
            if (FUSE_DOT) {
                // reduce across the quad's 16 lanes (l16 dimension)
#pragma unroll
                for (int off = 8; off > 0; off >>= 1)
                    rowsum += __shfl_xor(rowsum, off, 64);
                if (l16 == 0) atomicAdd(&dotv[row], rowsum);
            }
        }
    }
}

// ---------------------------------------------------------------------------
// final: out = y * (out - dot[row]); one block per row.
// ---------------------------------------------------------------------------
__global__ __launch_bounds__(256) void finish_replicator(const float* __restrict__ y,
                                                         float* __restrict__ out,
                                                         const float* __restrict__ dotv,
                                                         int N) {
    const int row = blockIdx.x;
    const float dot = dotv[row];
    const float4* y4 = (const float4*)(y + (size_t)row * N);
    float4* o4 = (float4*)(out + (size_t)row * N);
    const int n4 = N / 4;
    for (int i = threadIdx.x; i < n4; i += 256) {
        float4 a = y4[i], b = o4[i];
        float4 r;
        r.x = a.x * (b.x - dot);
        r.y = a.y * (b.y - dot);
        r.z = a.z * (b.z - dot);
        r.w = a.w * (b.w - dot);
        o4[i] = r;
    }
}

extern "C" void kernel_launch(void* const* d_in, const int* in_sizes, int n_in,
                              void* d_out, int out_size, void* d_ws, size_t ws_size,
                              hipStream_t stream) {
    // inputs: 0=t(1), 1=y(B*N), 2=W1(N*N), 3=b1(N), 4=W2(N*N), 5=b2(N)
    const float* y  = (const float*)d_in[1];
    const float* W1 = (const float*)d_in[2];
    const float* b1 = (const float*)d_in[3];
    const float* W2 = (const float*)d_in[4];
    const float* b2 = (const float*)d_in[5];

    const int N = in_sizes[3];            // 4096
    const int B = in_sizes[1] / N;        // 2048
    float* out = (float*)d_out;

    const size_t szY = (size_t)B * N;     // elements
    const size_t szW = (size_t)N * N;

    const int yn4 = (int)(szY / 4);
    const int wn4 = (int)(szW / 4);

    dim3 g1(N / 128, B / 128);            // 512 blocks, 4 waves each

    const size_t need_big = (szY + 2 * szW + szY) * sizeof(f16) + (size_t)B * 4;

    if (ws_size >= need_big) {
        f16* yb  = (f16*)d_ws;
        f16* w1b = yb + szY;
        f16* w2b = w1b + szW;
        f16* hb  = w2b + szW;
        float* dotv = (float*)(hb + szY);

        const int tot4 = yn4 + 2 * wn4;
        cvt3_f32_to_f16<<<(tot4 + 255) / 256, 256, 0, stream>>>(y, W1, W2, yb, w1b, w2b,
                                                                yn4, wn4);
        hipMemsetAsync(dotv, 0, (size_t)B * 4, stream);
        gemm_bt<1, 0><<<g1, 256, 0, stream>>>(yb, w1b, b1, hb, nullptr, nullptr, B, N, N);
        gemm_bt<0, 1><<<g1, 256, 0, stream>>>(hb, w2b, b2, out, y, dotv, B, N, N);
        finish_replicator<<<B, 256, 0, stream>>>(y, out, dotv, N);
    } else {
        // fallback: reuse one weight buffer (yb | wb | hb | dotv)
        f16* yb = (f16*)d_ws;
        f16* wb = yb + szY;
        f16* hb = wb + szW;
        float* dotv = (float*)(hb + szY);

        cvt_f32_to_f16<<<yn4 / 256, 256, 0, stream>>>(y, yb, yn4);
        cvt_f32_to_f16<<<wn4 / 256, 256, 0, stream>>>(W1, wb, wn4);
        hipMemsetAsync(dotv, 0, (size_t)B * 4, stream);
        gemm_bt<1, 0><<<g1, 256, 0, stream>>>(yb, wb, b1, hb, nullptr, nullptr, B, N, N);
        cvt_f32_to_f16<<<wn4 / 256, 256, 0, stream>>>(W2, wb, wn4);
        gemm_bt<0, 1><<<g1, 256, 0, stream>>>(hb, wb, b2, out, y, dotv, B, N, N);
        finish_replicator<<<B, 256, 0, stream>>>(y, out, dotv, N);
    }
}